// Round 1
// 866.391 us; speedup vs baseline: 1.2919x; 1.2919x over previous
//
#include <hip/hip_runtime.h>
#include <hip/hip_bf16.h>
#include <stdint.h>

typedef __bf16 bf16_t;
typedef bf16_t bf16x8 __attribute__((ext_vector_type(8)));
typedef float f32x4 __attribute__((ext_vector_type(4)));

#define MFMA16(a, b, c) __builtin_amdgcn_mfma_f32_16x16x32_bf16(a, b, c, 0, 0, 0)

static constexpr float kScale = 0.17677669529663687f;  // 1/sqrt(32)
static constexpr int CROWS = 25088;                    // 32 images per chunk
static constexpr int NCHUNK = 4;

__device__ __forceinline__ void gload16(const bf16_t* g, bf16_t* l) {
  __builtin_amdgcn_global_load_lds(
      (const __attribute__((address_space(1))) unsigned int*)g,
      (__attribute__((address_space(3))) unsigned int*)l, 16, 0, 0);
}

// ---------------------------------------------------------------------------
// k_prep: fp32 weights -> bf16 transposed (B^T layout for MFMA B-frags),
// fused bias_table[rel_index] + mask -> bmm[wi][h][i][j] fp32
// ---------------------------------------------------------------------------
__global__ __launch_bounds__(256) void k_prep(
    const float* __restrict__ wqkv,   // [512][1536] fp32
    const float* __restrict__ wproj,  // [512][512]  fp32
    const float* __restrict__ btab,   // [169][16]   fp32
    const float* __restrict__ mask,   // [16][49][49] fp32
    const int*   __restrict__ relidx, // [2401]
    bf16_t* __restrict__ wqkvT,       // [1536][512] bf16
    bf16_t* __restrict__ wprojT,      // [512][512]  bf16
    float*  __restrict__ bmm)         // [16][16][49][49] fp32
{
  int idx = blockIdx.x * 256 + threadIdx.x;
  if (idx < 1536 * 512) {
    int n = idx >> 9, k = idx & 511;
    wqkvT[idx] = (bf16_t)wqkv[k * 1536 + n];
  } else if (idx < 1536 * 512 + 512 * 512) {
    int t = idx - 1536 * 512;
    int n = t >> 9, k = t & 511;
    wprojT[t] = (bf16_t)wproj[k * 512 + n];
  } else if (idx < 1536 * 512 + 512 * 512 + 16 * 16 * 49 * 49) {
    int t = idx - (1536 * 512 + 512 * 512);
    int j = t % 49;  int t2 = t / 49;
    int i = t2 % 49; int t3 = t2 / 49;
    int h = t3 & 15; int wi = t3 >> 4;
    bmm[t] = btab[relidx[i * 49 + j] * 16 + h] + mask[(wi * 49 + i) * 49 + j];
  }
}

// ---------------------------------------------------------------------------
// k_cvt: x chunk fp32 -> bf16 (grid exact: 6272*256*8 = 25088*512)
// ---------------------------------------------------------------------------
__global__ __launch_bounds__(256) void k_cvt(
    const float* __restrict__ x, bf16_t* __restrict__ xb)
{
  size_t i = (size_t)(blockIdx.x * 256 + threadIdx.x) * 8;
  float4 f0 = *(const float4*)(x + i);
  float4 f1 = *(const float4*)(x + i + 4);
  bf16x8 v;
  v[0] = (bf16_t)f0.x; v[1] = (bf16_t)f0.y; v[2] = (bf16_t)f0.z; v[3] = (bf16_t)f0.w;
  v[4] = (bf16_t)f1.x; v[5] = (bf16_t)f1.y; v[6] = (bf16_t)f1.z; v[7] = (bf16_t)f1.w;
  *(bf16x8*)(xb + i) = v;
}

// ---------------------------------------------------------------------------
// k_gemm: 128x128 tile, BK=64, 4 waves (64x64 quadrant each), K=512.
// global_load_lds width-16 into LINEAR LDS; XOR-swizzle via pre-permuted
// global source (rule #21) + swizzled ds_read: byte ^= ((row&7)<<4).
// ISQKV: out bf16 [M][1536], +bias, cols<512 scaled by kScale (q).
// else : out fp32 [M][512], +bias.
// ---------------------------------------------------------------------------
template<int LDA, int NLD, bool ISQKV>
__global__ __launch_bounds__(256) void k_gemm(
    const bf16_t* __restrict__ A,      // [M][LDA] bf16
    const bf16_t* __restrict__ Bmat,   // [N][512] bf16
    const float*  __restrict__ bias,   // [N]
    bf16_t* __restrict__ outb,
    float*  __restrict__ outf)
{
  __shared__ alignas(16) bf16_t As[128 * 64];
  __shared__ alignas(16) bf16_t Bs[128 * 64];
  const int tid  = threadIdx.x;
  const int wv   = tid >> 6, lane = tid & 63;
  const int quad = lane >> 4, l16 = lane & 15;
  const int nt0 = blockIdx.x * 128, mt0 = blockIdx.y * 128;
  const int wr = (wv >> 1) * 64, wc = (wv & 1) * 64;

  // staging: wave wv stages rows [wv*32, wv*32+32) of both tiles.
  // call c: LDS linear bytes [wave_base + c*1024 + lane*16); the element that
  // must land there is row = wv*32+c*8+(lane>>3), col = 8*((lane&7)^(lane>>3))
  const int rsub = lane >> 3;                  // row&7 of staged row
  const int colp = ((lane & 7) ^ rsub) * 8;    // inverse-swizzled source col
  const bf16_t* ga = A    + (size_t)(mt0 + wv * 32 + rsub) * LDA + colp;
  const bf16_t* gb = Bmat + (size_t)(nt0 + wv * 32 + rsub) * 512 + colp;
  bf16_t* lA = As + wv * 32 * 64;
  bf16_t* lB = Bs + wv * 32 * 64;

  const f32x4 z4 = {0.f, 0.f, 0.f, 0.f};
  f32x4 acc[4][4];
#pragma unroll
  for (int a = 0; a < 4; ++a)
#pragma unroll
    for (int b = 0; b < 4; ++b) acc[a][b] = z4;

  for (int kt = 0; kt < 8; ++kt) {
    const int k0 = kt * 64;
#pragma unroll
    for (int c = 0; c < 4; ++c) {
      gload16(ga + (size_t)c * 8 * LDA + k0, lA + c * 512);
      gload16(gb + c * 8 * 512 + k0, lB + c * 512);
    }
    __syncthreads();   // compiler drains vmcnt(0) here (gload_lds complete)
#pragma unroll
    for (int kk = 0; kk < 2; ++kk) {
      bf16x8 af[4], bfr[4];
#pragma unroll
      for (int mt = 0; mt < 4; ++mt) {
        int row = wr + mt * 16 + l16;          // row&7 == l16&7
        af[mt] = *(const bf16x8*)&As[row * 64 + ((kk * 32 + quad * 8) ^ ((l16 & 7) * 8))];
      }
#pragma unroll
      for (int nt = 0; nt < 4; ++nt) {
        int row = wc + nt * 16 + l16;
        bfr[nt] = *(const bf16x8*)&Bs[row * 64 + ((kk * 32 + quad * 8) ^ ((l16 & 7) * 8))];
      }
#pragma unroll
      for (int mt = 0; mt < 4; ++mt)
#pragma unroll
        for (int nt = 0; nt < 4; ++nt)
          acc[mt][nt] = MFMA16(af[mt], bfr[nt], acc[mt][nt]);
    }
    __syncthreads();
  }

#pragma unroll
  for (int nt = 0; nt < 4; ++nt) {
    int col = nt0 + wc + nt * 16 + l16;
    float bv = bias[col];
#pragma unroll
    for (int mt = 0; mt < 4; ++mt) {
#pragma unroll
      for (int r = 0; r < 4; ++r) {
        size_t row = (size_t)(mt0 + wr + mt * 16 + quad * 4 + r);
        float v = acc[mt][nt][r] + bv;
        if constexpr (ISQKV) {
          if (col < 512) v *= kScale;          // fuse q-scale
          outb[row * NLD + col] = (bf16_t)v;
        } else {
          outf[row * NLD + col] = v;
        }
      }
    }
  }
}

// ---------------------------------------------------------------------------
// k_attn2: one block per (window, 4 heads); wave = one head, fully private.
// q/k read DIRECTLY from global as frag-shaped bf16x8 loads (no LDS).
// Only P[64][64] and V^T[32][64] in LDS, XOR-swizzled (byte ^= (row&7)<<4).
// Output overwrites the q-slot of qkv (q is dead after S).
// ---------------------------------------------------------------------------
__global__ __launch_bounds__(256) void k_attn2(
    bf16_t* __restrict__ qkv,          // [CROWS][1536] bf16
    const float* __restrict__ bmm)     // [16][16][49][49]
{
  __shared__ alignas(16) bf16_t lds[4 * 6144];   // per wave: ps 4096 + vts 2048
  const int tid  = threadIdx.x;
  const int wv   = tid >> 6, lane = tid & 63;
  const int quad = lane >> 4, l16 = lane & 15;
  const int h = blockIdx.x * 4 + wv;
  const int w = blockIdx.y;
  const int bimg = w >> 4, wi = w & 15;
  const int rowbase = bimg * 784 + (wi >> 2) * 196 + (wi & 3) * 7;
  char* ps  = (char*)(lds + wv * 6144);          // P  [64][64] swizzled
  char* vts = (char*)(lds + wv * 6144 + 4096);   // V^T [32][64] swizzled

  // zero v^T cols 48..63 (tail tokens) so 0*garbage can't make NaN
  for (int u = lane; u < 32 * 16; u += 64) {
    int d = u >> 4, j = 48 + (u & 15);
    *(bf16_t*)(vts + ((d * 128 + j * 2) ^ ((d & 7) << 4))) = (bf16_t)0.f;
  }
  // stage V transposed: read v rows vectorized, scatter bf16 into swizzled V^T
  const bf16_t* vbase = qkv + 1024 + h * 32;
  for (int u = lane; u < 49 * 4; u += 64) {
    int l = u >> 2, dg = u & 3;
    size_t r = (size_t)(rowbase + (l / 7) * 28 + (l % 7));
    bf16x8 vvv = *(const bf16x8*)(vbase + r * 1536 + dg * 8);
#pragma unroll
    for (int e = 0; e < 8; ++e) {
      int d = dg * 8 + e;
      *(bf16_t*)(vts + ((d * 128 + l * 2) ^ ((d & 7) << 4))) = vvv[e];
    }
  }

  // ---- S = q @ k^T  (q,k frags straight from global; rows>=49 clamp to 48) --
  const bf16_t* qbase = qkv + h * 32;
  const bf16_t* kbase = qkv + 512 + h * 32;
  const f32x4 z4 = {0.f, 0.f, 0.f, 0.f};
  f32x4 sacc[4][4];
#pragma unroll
  for (int a = 0; a < 4; ++a)
#pragma unroll
    for (int b = 0; b < 4; ++b) sacc[a][b] = z4;

  bf16x8 kb[4];
#pragma unroll
  for (int nt = 0; nt < 4; ++nt) {
    int t = nt * 16 + l16; if (t > 48) t = 48;
    size_t r = (size_t)(rowbase + (t / 7) * 28 + (t % 7));
    kb[nt] = *(const bf16x8*)(kbase + r * 1536 + quad * 8);
  }
#pragma unroll
  for (int mt = 0; mt < 4; ++mt) {
    int t = mt * 16 + l16; if (t > 48) t = 48;
    size_t r = (size_t)(rowbase + (t / 7) * 28 + (t % 7));
    bf16x8 qa = *(const bf16x8*)(qbase + r * 1536 + quad * 8);
#pragma unroll
    for (int nt = 0; nt < 4; ++nt) sacc[mt][nt] = MFMA16(qa, kb[nt], sacc[mt][nt]);
  }

  // ---- +bias+mask, softmax (16-wide shfl), P -> swizzled LDS ----
  const float* bm = bmm + (wi * 16 + h) * 2401;
#pragma unroll
  for (int mt = 0; mt < 4; ++mt) {
#pragma unroll
    for (int rr = 0; rr < 4; ++rr) {
      int i = mt * 16 + quad * 4 + rr;
      bool iv = (i < 49);
      float sv[4], mx = -3e38f;
#pragma unroll
      for (int nt = 0; nt < 4; ++nt) {
        int j = nt * 16 + l16;
        sv[nt] = (iv && j < 49) ? (sacc[mt][nt][rr] + bm[i * 49 + j]) : -3e38f;
        mx = fmaxf(mx, sv[nt]);
      }
#pragma unroll
      for (int off = 1; off < 16; off <<= 1) mx = fmaxf(mx, __shfl_xor(mx, off, 16));
      float ex[4], sum = 0.f;
#pragma unroll
      for (int nt = 0; nt < 4; ++nt) {
        ex[nt] = (sv[nt] > -2e38f) ? __expf(sv[nt] - mx) : 0.f;
        sum += ex[nt];
      }
#pragma unroll
      for (int off = 1; off < 16; off <<= 1) sum += __shfl_xor(sum, off, 16);
      float rinv = (sum > 0.f) ? (1.f / sum) : 0.f;
#pragma unroll
      for (int nt = 0; nt < 4; ++nt) {
        int j = nt * 16 + l16;
        *(bf16_t*)(ps + ((i * 128 + j * 2) ^ ((i & 7) << 4))) = (bf16_t)(ex[nt] * rinv);
      }
    }
  }

  asm volatile("" ::: "memory");   // keep ds_writes above the ds_reads below

  // ---- O = P @ V  (wave-private LDS, no barrier needed) ----
  f32x4 oacc[4][2];
#pragma unroll
  for (int a = 0; a < 4; ++a) { oacc[a][0] = z4; oacc[a][1] = z4; }
#pragma unroll
  for (int kk = 0; kk < 2; ++kk) {
    bf16x8 vb[2];
#pragma unroll
    for (int nt = 0; nt < 2; ++nt) {
      int d = nt * 16 + l16;
      vb[nt] = *(const bf16x8*)(vts + ((d * 128 + (kk * 32 + quad * 8) * 2) ^ ((d & 7) << 4)));
    }
#pragma unroll
    for (int mt = 0; mt < 4; ++mt) {
      int i = mt * 16 + l16;
      bf16x8 pa = *(const bf16x8*)(ps + ((i * 128 + (kk * 32 + quad * 8) * 2) ^ ((i & 7) << 4)));
#pragma unroll
      for (int nt = 0; nt < 2; ++nt) oacc[mt][nt] = MFMA16(pa, vb[nt], oacc[mt][nt]);
    }
  }

  // ---- write O over the q-slot ----
  bf16_t* obase = qkv + h * 32;
#pragma unroll
  for (int mt = 0; mt < 4; ++mt) {
#pragma unroll
    for (int rr = 0; rr < 4; ++rr) {
      int l = mt * 16 + quad * 4 + rr;
      if (l < 49) {
        size_t r = (size_t)(rowbase + (l / 7) * 28 + (l % 7));
#pragma unroll
        for (int nt = 0; nt < 2; ++nt)
          obase[r * 1536 + nt * 16 + l16] = (bf16_t)oacc[mt][nt][rr];
      }
    }
  }
}

// ---------------------------------------------------------------------------
// Workspace (exactly 107,316,224 B == previous kernel's proven footprint):
//   wqkvT 1,572,864 | wprojT 524,288 | bmm 2,458,624 | xb 25,690,112
//   qkv (chunk) 77,070,336
// ---------------------------------------------------------------------------
extern "C" void kernel_launch(void* const* d_in, const int* in_sizes, int n_in,
                              void* d_out, int out_size, void* d_ws, size_t ws_size,
                              hipStream_t stream) {
  const float* x     = (const float*)d_in[0];
  const float* mask  = (const float*)d_in[1];
  const float* wqkv  = (const float*)d_in[2];
  const float* bqkv  = (const float*)d_in[3];
  const float* btab  = (const float*)d_in[4];
  const float* wproj = (const float*)d_in[5];
  const float* bproj = (const float*)d_in[6];
  const int*   relix = (const int*)d_in[7];
  float* out = (float*)d_out;

  char* ws = (char*)d_ws;
  bf16_t* wqkvT  = (bf16_t*)(ws);
  bf16_t* wprojT = (bf16_t*)(ws + 1572864);
  float*  bmm    = (float*)(ws + 2097152);
  bf16_t* xb     = (bf16_t*)(ws + 4555776);
  bf16_t* qkv    = (bf16_t*)(ws + 30245888);

  k_prep<<<6497, 256, 0, stream>>>(wqkv, wproj, btab, mask, relix, wqkvT, wprojT, bmm);
  for (int c = 0; c < NCHUNK; ++c) {
    const float* xc = x + (size_t)c * CROWS * 512;
    k_cvt<<<6272, 256, 0, stream>>>(xc, xb);
    k_gemm<512, 1536, true><<<dim3(12, 196), 256, 0, stream>>>(xb, wqkvT, bqkv, qkv, nullptr);
    k_attn2<<<dim3(4, 512), 256, 0, stream>>>(qkv, bmm);
    k_gemm<1536, 512, false><<<dim3(4, 196), 256, 0, stream>>>(qkv, wprojT, bproj, nullptr,
                                                               out + (size_t)c * CROWS * 512);
  }
}